// Round 8
// baseline (1034.329 us; speedup 1.0000x reference)
//
#include <hip/hip_runtime.h>

// GATrNet forward, MI355X/gfx950.
// Precision: q exact via f16 hi/lo split (hn hi/lo planes -> K=1024 qkv GEMM,
// q stored hi+lo); k stored f16-rounded only (error budget: r2/r3 bracket puts
// one storage source at ~4.1e4 vs 6.26e4 threshold). S = (qhi+qlo)*khi.
// Flash r8: software-pipelined staging, AITER-style. Raw s_barrier (asm, no
// implicit vmcnt(0) drain) + hand s_waitcnt vmcnt(N): K-stage (16KB) issued
// after S reads kp, drains at next tile's vmcnt(8); V-stage (32KB) issued
// after PV reads vp, drains at same-tile vmcnt(4). Alpha rescale unconditional
// (r7's flag-gating regressed). 48KB image/tile, zero global loads in loop.

typedef unsigned short u16;
typedef unsigned int u32;
typedef __attribute__((ext_vector_type(4))) float f32x4;
typedef __attribute__((ext_vector_type(8))) _Float16 half8;

__device__ inline u16 f2h(float f) {
  _Float16 h = (_Float16)f;
  return __builtin_bit_cast(u16, h);
}
__device__ inline float h2f(u16 u) { return (float)__builtin_bit_cast(_Float16, u); }

// async global->LDS, 16B per lane. LDS dest = wave-uniform base + lane*16.
__device__ inline void async_cp16(const void* g, void* l) {
  __builtin_amdgcn_global_load_lds((const __attribute__((address_space(1))) u32*)g,
                                   (__attribute__((address_space(3))) u32*)l, 16, 0, 0);
}

__device__ inline f32x4 mfma16(half8 a, half8 b, f32x4 c) {
  return __builtin_amdgcn_mfma_f32_16x16x32_f16(a, b, c, 0, 0, 0);
}

// DPP row_ror move within 16-lane rows (reduction domain = lane&15).
template <int CTRL>
__device__ inline float dpp_mv(float v) {
  int i = __builtin_bit_cast(int, v);
  return __builtin_bit_cast(float, __builtin_amdgcn_update_dpp(i, i, CTRL, 0xf, 0xf, false));
}

#define HW_BARRIER() asm volatile("s_barrier" ::: "memory")
#define WAIT_VM8() asm volatile("s_waitcnt vmcnt(8)" ::: "memory")
#define WAIT_VM4_LGKM0() asm volatile("s_waitcnt vmcnt(4) lgkmcnt(0)" ::: "memory")

// INNER_COORDS {0,2,3,4,8,9,10,14} packed 4b each
#define IC_PACK 0xEA984320u

// q buffer row: [q_hi 0,2048) [q_lo 2048,4096)
#define Q_LD 4096
// packed KV block per (b,tile): u16 offsets, stride 24576 (48KB)
//   kp [0,8192):     key*256 + (((d>>3)^(key&7))<<3) + (d&7)
//   vp [8192,24576): vd*32 + (((key>>3)^((vd>>1)&3))<<3) + (key&7)
#define KV_STRIDE 24576

// ---------------- weight prep ----------------
__global__ void build_wb_enter(const float* __restrict__ we, const float* __restrict__ blade,
                               float* __restrict__ out) {
  int idx = blockIdx.x * 256 + threadIdx.x;
  if (idx >= 32 * 48 * 16) return;
  int j = idx / 768;
  int rem = idx - j * 768;
  int ix = rem >> 4, y = rem & 15;
  int i = ix >> 4, x = ix & 15;
  float acc = 0.f;
#pragma unroll
  for (int bb = 0; bb < 9; ++bb) acc += we[j * 27 + i * 9 + bb] * blade[bb * 256 + x * 16 + y];
  out[idx] = acc;
}

// WqkvT[n][k] f16, K=1024 (k>=512 duplicates k-512 so GEMM computes (hi+lo)*w).
__global__ void build_wqkvT(const float* __restrict__ wq, const float* __restrict__ wk,
                            const float* __restrict__ wv, const float* __restrict__ blade,
                            u16* __restrict__ out) {
  int idx = blockIdx.x * 256 + threadIdx.x;
  if (idx >= 2816 * 1024) return;
  int k = idx & 1023, n = idx >> 10;
  int kk = k & 511;
  int i = kk >> 4, x = kk & 15;
  const float* w;
  int y;
  float scale = 1.0f;
  if (n < 2048) {
    int j = n >> 3;
    y = (IC_PACK >> ((n & 7) * 4)) & 15;
    w = wq + j * 288 + i * 9;
    scale = 0.09016844005556021f;  // (1/16)*log2(e)
  } else if (n < 2304) {
    int m = n - 2048;
    int j = m >> 3;
    y = (IC_PACK >> ((m & 7) * 4)) & 15;
    w = wk + j * 288 + i * 9;
  } else {
    int m = n - 2304;
    int j = m >> 4;
    y = m & 15;
    w = wv + j * 288 + i * 9;
  }
  float acc = 0.f;
#pragma unroll
  for (int bb = 0; bb < 9; ++bb) acc += w[bb] * blade[bb * 256 + x * 16 + y];
  out[idx] = f2h(acc * scale);
}

// WoutT[n][k] f16: n=(j,y)<512, k=(c,x)<4096
__global__ void build_woutT(const float* __restrict__ wo, const float* __restrict__ blade,
                            u16* __restrict__ out) {
  int idx = blockIdx.x * 256 + threadIdx.x;
  if (idx >= 512 * 4096) return;
  int k = idx & 4095, n = idx >> 12;
  int j = n >> 4, y = n & 15;
  int c = k >> 4, x = k & 15;
  float acc = 0.f;
#pragma unroll
  for (int bb = 0; bb < 9; ++bb) acc += wo[j * 2304 + c * 9 + bb] * blade[bb * 256 + x * 16 + y];
  out[idx] = f2h(acc);
}

// WfinalT[n][k] f16: n=(j,y)<512, k=(i,x)<512
__global__ void build_wfinalT(const float* __restrict__ wf, const float* __restrict__ blade,
                              u16* __restrict__ out) {
  int idx = blockIdx.x * 256 + threadIdx.x;
  if (idx >= 512 * 512) return;
  int k = idx & 511, n = idx >> 9;
  int j = n >> 4, y = n & 15;
  int i = k >> 4, x = k & 15;
  float acc = 0.f;
#pragma unroll
  for (int bb = 0; bb < 9; ++bb) acc += wf[j * 288 + i * 9 + bb] * blade[bb * 256 + x * 16 + y];
  out[idx] = f2h(acc);
}

// ---------------- enter projection + equi_norm ----------------
__global__ __launch_bounds__(256) void enter_norm(const float* __restrict__ x,
                                                  const float* __restrict__ wb,
                                                  float* __restrict__ h, u16* __restrict__ hn) {
  const int tid = threadIdx.x;
  const int tl = tid >> 5, j = tid & 31;
  const int token = blockIdx.x * 8 + tl;
  const float* xp = x + (size_t)token * 48;
  float xv[48];
#pragma unroll
  for (int q = 0; q < 12; ++q) {
    float4 t = ((const float4*)xp)[q];
    xv[q * 4 + 0] = t.x;
    xv[q * 4 + 1] = t.y;
    xv[q * 4 + 2] = t.z;
    xv[q * 4 + 3] = t.w;
  }
  float acc[16] = {};
  const float* wp = wb + j * 768;
#pragma unroll
  for (int t = 0; t < 48; ++t) {
    const float xs = xv[t];
    const float4* w4 = (const float4*)(wp + t * 16);
#pragma unroll
    for (int u = 0; u < 4; ++u) {
      float4 wv = w4[u];
      acc[u * 4 + 0] += xs * wv.x;
      acc[u * 4 + 1] += xs * wv.y;
      acc[u * 4 + 2] += xs * wv.z;
      acc[u * 4 + 3] += xs * wv.w;
    }
  }
  float ip = acc[0] * acc[0] + acc[2] * acc[2] + acc[3] * acc[3] + acc[4] * acc[4] +
             acc[8] * acc[8] + acc[9] * acc[9] + acc[10] * acc[10] + acc[14] * acc[14];
#pragma unroll
  for (int d = 1; d < 32; d <<= 1) ip += __shfl_xor(ip, d, 64);
  const float r = 1.0f / sqrtf(ip * (1.0f / 32.0f));
  float* hp = h + (size_t)token * 512 + j * 16;
#pragma unroll
  for (int u = 0; u < 4; ++u)
    ((float4*)hp)[u] = make_float4(acc[u * 4 + 0], acc[u * 4 + 1], acc[u * 4 + 2], acc[u * 4 + 3]);
  u16 hb[16], lb[16];
#pragma unroll
  for (int y = 0; y < 16; ++y) {
    float sv = acc[y] * r;
    u16 hv = f2h(sv);
    hb[y] = hv;
    lb[y] = f2h(sv - h2f(hv));
  }
  u16* hq = hn + (size_t)token * 1024 + j * 16;
  ((uint4*)hq)[0] = *(const uint4*)&hb[0];
  ((uint4*)hq)[1] = *(const uint4*)&hb[8];
  u16* lq = hq + 512;
  ((uint4*)lq)[0] = *(const uint4*)&lb[0];
  ((uint4*)lq)[1] = *(const uint4*)&lb[8];
}

// ---------------- 128x128 f16 MFMA GEMM, B transposed [N][K] ----------------
// MODE 0: qkv -> q hi/lo rows of Co (ldc=4096); k (f16) + v into packed kvp
//         blocks (48KB LDS-image layout, swizzle baked in; V 8B-vectorized)
// MODE 1: outp -> Co f16 = (acc + res)/256
// MODE 2: final-> Cf fp32 = acc*256
template <int MODE>
__global__ __launch_bounds__(256) void gemm_bt(const u16* __restrict__ A,
                                               const u16* __restrict__ BT, int M, int N, int K,
                                               u16* __restrict__ Co, float* __restrict__ Cf,
                                               const float* __restrict__ res,
                                               u16* __restrict__ kvp, int ldc) {
  __shared__ u16 ltA[4096];  // [128][32], chunk-swizzled
  __shared__ u16 ltB[4096];
  const int tid = threadIdx.x;
  const int lane = tid & 63;
  const int wid = tid >> 6;
  const int quad = lane >> 4, colc = lane & 15;
  const int m0 = blockIdx.y * 128, n0 = blockIdx.x * 128;
  const int wrow = (wid >> 1) * 64, wcol = (wid & 1) * 64;
  f32x4 acc[4][4] = {};
  const int r0 = tid >> 2;
  const int swk = (((tid & 3) ^ ((tid >> 2) & 3)) << 3);
  const u16* Ab = A + (size_t)(m0 + r0) * K + swk;
  const u16* Ab2 = Ab + (size_t)64 * K;
  const u16* Bb = BT + (size_t)(n0 + r0) * K + swk;
  const u16* Bb2 = Bb + (size_t)64 * K;
  const int swr = ((colc & 3) << 3);
  for (int k0 = 0; k0 < K; k0 += 32) {
    __syncthreads();
    async_cp16(Ab + k0, &ltA[tid * 8]);
    async_cp16(Ab2 + k0, &ltA[2048 + tid * 8]);
    async_cp16(Bb + k0, &ltB[tid * 8]);
    async_cp16(Bb2 + k0, &ltB[2048 + tid * 8]);
    __syncthreads();
    half8 af[4], bfr[4];
#pragma unroll
    for (int i2 = 0; i2 < 4; ++i2)
      af[i2] = *(const half8*)&ltA[(wrow + i2 * 16 + colc) * 32 + ((quad << 3) ^ swr)];
#pragma unroll
    for (int j2 = 0; j2 < 4; ++j2)
      bfr[j2] = *(const half8*)&ltB[(wcol + j2 * 16 + colc) * 32 + ((quad << 3) ^ swr)];
#pragma unroll
    for (int i2 = 0; i2 < 4; ++i2)
#pragma unroll
      for (int j2 = 0; j2 < 4; ++j2) acc[i2][j2] = mfma16(af[i2], bfr[j2], acc[i2][j2]);
  }
#pragma unroll
  for (int i2 = 0; i2 < 4; ++i2) {
#pragma unroll
    for (int j2 = 0; j2 < 4; ++j2) {
      const int mb = m0 + wrow + i2 * 16 + quad * 4;
      const int n = n0 + wcol + j2 * 16 + colc;
      if constexpr (MODE == 0) {
        if (n < 2048) {
#pragma unroll
          for (int rg = 0; rg < 4; ++rg) {
            const int m = mb + rg;
            float v = acc[i2][j2][rg];
            u16 hv = f2h(v);
            Co[(size_t)m * ldc + n] = hv;
            Co[(size_t)m * ldc + 2048 + n] = f2h(v - h2f(hv));
          }
        } else if (n < 2304) {
          const int d = n - 2048;
#pragma unroll
          for (int rg = 0; rg < 4; ++rg) {
            const int m = mb + rg;
            int bb2 = m >> 11, s = m & 2047, t = s >> 5, key = s & 31;
            size_t blk = (size_t)(bb2 * 64 + t) * KV_STRIDE;
            int off2 = key * 256 + ((((d >> 3) ^ (key & 7)) << 3)) + (d & 7);
            kvp[blk + off2] = f2h(acc[i2][j2][rg]);
          }
        } else {
          const int vd = n - 2304;
          int bb2 = mb >> 11, s0 = mb & 2047, t = s0 >> 5, key0 = s0 & 31;
          size_t blk = (size_t)(bb2 * 64 + t) * KV_STRIDE;
          u16 tmp[4];
#pragma unroll
          for (int rg = 0; rg < 4; ++rg) tmp[rg] = f2h(acc[i2][j2][rg]);
          size_t idx =
              blk + 8192 + vd * 32 + ((((key0 >> 3) ^ ((vd >> 1) & 3)) << 3)) + (key0 & 7);
          *(uint2*)&kvp[idx] = *(const uint2*)tmp;
        }
      } else {
#pragma unroll
        for (int rg = 0; rg < 4; ++rg) {
          const int m = mb + rg;
          float v = acc[i2][j2][rg];
          if constexpr (MODE == 1) {
            v += res[(size_t)m * ldc + n];
            Co[(size_t)m * ldc + n] = f2h(v * (1.0f / 256.0f));
          } else {
            Cf[(size_t)m * ldc + n] = v * 256.0f;
          }
        }
      }
    }
  }
}

// ---------------- flash attention ----------------
// grid (qblock=32, head=8, batch=4), 256 thr. Pipelined: per tile
//   vmcnt(8) + bar  -> S (32 MFMA, reads kp)
//   bar             -> issue K-stage(it+1) [4 cp16]
//   softmax (DPP) + pbuf writes
//   vmcnt(4)+lgkm0 + bar -> PV (rescale + 32 MFMA, reads vp/pbuf/alpha)
//   bar             -> issue V-stage(it+1) [8 cp16]
// No __syncthreads in loop => no vmcnt(0) drains; copies overlap compute.
__global__ __launch_bounds__(256, 2) void flash_attn(const u16* __restrict__ qbuf,
                                                     const u16* __restrict__ kvp,
                                                     u16* __restrict__ out) {
  __shared__ u16 lds[27392];
  u16* kp = lds;                            // [32 keys][256 d] swizzled, 16KB
  u16* vp = lds + 8192;                     // [512 vd][32 keys] swizzled, 32KB
  u16* pbuf = lds + 24576;                  // [64 qrow][40]
  float* alpha_s = (float*)(lds + 27136);   // 64 floats
  float* l_s = (float*)(lds + 27264);       // 64 floats
  const int tid = threadIdx.x, lane = tid & 63, wid = tid >> 6;
  const int quad = lane >> 4, colc = lane & 15;
  const int b = blockIdx.z, h = blockIdx.y, qb = blockIdx.x;
  half8 qh[8], ql[8];
  {
    const u16* qr = qbuf + (size_t)(b * 2048 + qb * 64 + wid * 16 + colc) * Q_LD + h * 8;
#pragma unroll
    for (int kb = 0; kb < 8; ++kb) {
      qh[kb] = *(const half8*)(qr + (kb * 4 + quad) * 64);
      ql[kb] = *(const half8*)(qr + 2048 + (kb * 4 + quad) * 64);
    }
  }
  f32x4 oacc[4][8] = {};
  float mrun[4], lrun[4];
#pragma unroll
  for (int rg = 0; rg < 4; ++rg) {
    mrun[rg] = -1e30f;
    lrun[rg] = 0.f;
  }
  const u16* kvb = kvp + (size_t)b * 64 * KV_STRIDE;
  const int x0 = colc & 7;
  // prologue: stage tile 0 (K then V; order defines vmcnt retirement)
  {
    const u16* src = kvb;
#pragma unroll
    for (int c = 0; c < 4; ++c) {
      int e = c * 256 + tid;
      async_cp16(src + e * 8, &lds[e * 8]);
    }
#pragma unroll
    for (int c = 0; c < 8; ++c) {
      int e = c * 256 + tid;
      async_cp16(src + 8192 + e * 8, &lds[8192 + e * 8]);
    }
  }
  for (int it = 0; it < 64; ++it) {
    WAIT_VM8();  // retire K-stage(it); V-stage(it) stays in flight
    HW_BARRIER();
    // S [16q x 32k]: (qhi+qlo)*khi, 4 accumulation chains
    f32x4 s0a = {}, s0b = {}, s1a = {}, s1b = {};
#pragma unroll
    for (int kb = 0; kb < 8; ++kb) {
      const int sw = (((kb * 4 + quad) ^ x0) << 3);
      half8 khi0 = *(const half8*)&kp[colc * 256 + sw];
      half8 khi1 = *(const half8*)&kp[(16 + colc) * 256 + sw];
      s0a = mfma16(qh[kb], khi0, s0a);
      s0b = mfma16(ql[kb], khi0, s0b);
      s1a = mfma16(qh[kb], khi1, s1a);
      s1b = mfma16(ql[kb], khi1, s1b);
    }
    f32x4 sfr[2];
    sfr[0] = s0a + s0b;
    sfr[1] = s1a + s1b;
    HW_BARRIER();  // all waves done reading kp -> safe to overwrite
    {
      const int itn = (it < 63) ? it + 1 : 63;
      const u16* src = kvb + (size_t)itn * KV_STRIDE;
#pragma unroll
      for (int c = 0; c < 4; ++c) {
        int e = c * 256 + tid;
        async_cp16(src + e * 8, &lds[e * 8]);
      }
    }
    // online softmax (exp2 domain), DPP row_ror butterflies over colc
    float mx[4];
#pragma unroll
    for (int rg = 0; rg < 4; ++rg) mx[rg] = fmaxf(sfr[0][rg], sfr[1][rg]);
#pragma unroll
    for (int rg = 0; rg < 4; ++rg) mx[rg] = fmaxf(mx[rg], dpp_mv<0x121>(mx[rg]));
#pragma unroll
    for (int rg = 0; rg < 4; ++rg) mx[rg] = fmaxf(mx[rg], dpp_mv<0x122>(mx[rg]));
#pragma unroll
    for (int rg = 0; rg < 4; ++rg) mx[rg] = fmaxf(mx[rg], dpp_mv<0x124>(mx[rg]));
#pragma unroll
    for (int rg = 0; rg < 4; ++rg) mx[rg] = fmaxf(mx[rg], dpp_mv<0x128>(mx[rg]));
    float al[4], pv0[4], pv1[4], rs[4];
#pragma unroll
    for (int rg = 0; rg < 4; ++rg) {
      float mn = fmaxf(mrun[rg], mx[rg]);
      al[rg] = exp2f(mrun[rg] - mn);
      mrun[rg] = mn;
      pv0[rg] = exp2f(sfr[0][rg] - mn);
      pv1[rg] = exp2f(sfr[1][rg] - mn);
      rs[rg] = pv0[rg] + pv1[rg];
    }
#pragma unroll
    for (int rg = 0; rg < 4; ++rg) rs[rg] += dpp_mv<0x121>(rs[rg]);
#pragma unroll
    for (int rg = 0; rg < 4; ++rg) rs[rg] += dpp_mv<0x122>(rs[rg]);
#pragma unroll
    for (int rg = 0; rg < 4; ++rg) rs[rg] += dpp_mv<0x124>(rs[rg]);
#pragma unroll
    for (int rg = 0; rg < 4; ++rg) rs[rg] += dpp_mv<0x128>(rs[rg]);
    const int prow = wid * 16 + quad * 4;
#pragma unroll
    for (int rg = 0; rg < 4; ++rg) {
      lrun[rg] = lrun[rg] * al[rg] + rs[rg];
      pbuf[(prow + rg) * 40 + colc] = f2h(pv0[rg]);
      pbuf[(prow + rg) * 40 + 16 + colc] = f2h(pv1[rg]);
    }
    if (colc == 0) {
#pragma unroll
      for (int rg = 0; rg < 4; ++rg) alpha_s[prow + rg] = al[rg];
    }
    WAIT_VM4_LGKM0();  // retire V-stage(it) (K-stage(it+1) in flight); drain pbuf writes
    HW_BARRIER();      // pbuf/alpha published; vp(it) valid for all waves
    // PV: this wave's 128 v-dims, all 64 q-rows
    half8 vf[8];
#pragma unroll
    for (int vb = 0; vb < 8; ++vb) {
      const int vd = wid * 128 + vb * 16 + colc;
      vf[vb] = *(const half8*)&vp[vd * 32 + ((quad ^ ((vd >> 1) & 3)) << 3)];
    }
    half8 pf[4];
#pragma unroll
    for (int pa = 0; pa < 4; ++pa) pf[pa] = *(const half8*)&pbuf[(pa * 16 + colc) * 40 + quad * 8];
    float av[4][4];
#pragma unroll
    for (int pa = 0; pa < 4; ++pa)
#pragma unroll
      for (int rg = 0; rg < 4; ++rg) av[pa][rg] = alpha_s[pa * 16 + quad * 4 + rg];
#pragma unroll
    for (int pa = 0; pa < 4; ++pa)
#pragma unroll
      for (int vb = 0; vb < 8; ++vb)
#pragma unroll
        for (int rg = 0; rg < 4; ++rg) oacc[pa][vb][rg] *= av[pa][rg];
#pragma unroll
    for (int vb = 0; vb < 8; ++vb)
#pragma unroll
      for (int pa = 0; pa < 4; ++pa) oacc[pa][vb] = mfma16(pf[pa], vf[vb], oacc[pa][vb]);
    HW_BARRIER();  // all waves done reading vp/pbuf -> safe to overwrite vp
    {
      const int itn = (it < 63) ? it + 1 : 63;
      const u16* src = kvb + (size_t)itn * KV_STRIDE;
#pragma unroll
      for (int c = 0; c < 8; ++c) {
        int e = c * 256 + tid;
        async_cp16(src + 8192 + e * 8, &lds[8192 + e * 8]);
      }
    }
  }
  {
    const int prow = wid * 16 + quad * 4;
    if (colc == 0) {
#pragma unroll
      for (int rg = 0; rg < 4; ++rg) l_s[prow + rg] = lrun[rg];
    }
  }
  __syncthreads();
  u16* ob = out + ((size_t)b * 2048 + qb * 64) * 4096 + h * 512 + wid * 128;
#pragma unroll
  for (int pa = 0; pa < 4; ++pa) {
    float li[4];
#pragma unroll
    for (int rg = 0; rg < 4; ++rg) li[rg] = 1.0f / l_s[pa * 16 + quad * 4 + rg];
#pragma unroll
    for (int vb = 0; vb < 8; ++vb)
#pragma unroll
      for (int rg = 0; rg < 4; ++rg)
        ob[(size_t)(pa * 16 + quad * 4 + rg) * 4096 + vb * 16 + colc] =
            f2h(oacc[pa][vb][rg] * li[rg]);
  }
}

// ---------------- launcher ----------------
extern "C" void kernel_launch(void* const* d_in, const int* in_sizes, int n_in, void* d_out,
                              int out_size, void* d_ws, size_t ws_size, hipStream_t stream) {
  const float* x = (const float*)d_in[0];
  const float* blade = (const float*)d_in[1];
  const float* w_enter = (const float*)d_in[2];
  const float* w_q = (const float*)d_in[3];
  const float* w_k = (const float*)d_in[4];
  const float* w_v = (const float*)d_in[5];
  const float* w_out = (const float*)d_in[6];
  const float* w_final = (const float*)d_in[7];
  float* out = (float*)d_out;

  char* ws = (char*)d_ws;
  size_t off = 0;
  auto alloc = [&](size_t bytes) {
    void* p = ws + off;
    off = (off + bytes + 255) & ~(size_t)255;
    return p;
  };
  float* wb_enter = (float*)alloc((size_t)32 * 48 * 16 * 4);
  u16* wqkvT = (u16*)alloc((size_t)2816 * 1024 * 2);
  u16* woutT = (u16*)alloc((size_t)512 * 4096 * 2);
  u16* wfinT = (u16*)alloc((size_t)512 * 512 * 2);
  float* hbuf = (float*)alloc((size_t)8192 * 512 * 4);
  u16* hn2 = (u16*)alloc((size_t)8192 * 1024 * 2);
  u16* qbuf = (u16*)alloc((size_t)8192 * Q_LD * 2);
  u16* kvp = (u16*)alloc((size_t)4 * 64 * KV_STRIDE * 2);
  u16* attno = (u16*)alloc((size_t)8192 * 4096 * 2);
  u16* h2 = (u16*)alloc((size_t)8192 * 512 * 2);

  build_wb_enter<<<96, 256, 0, stream>>>(w_enter, blade, wb_enter);
  build_wqkvT<<<11264, 256, 0, stream>>>(w_q, w_k, w_v, blade, wqkvT);
  build_woutT<<<8192, 256, 0, stream>>>(w_out, blade, woutT);
  build_wfinalT<<<1024, 256, 0, stream>>>(w_final, blade, wfinT);
  enter_norm<<<1024, 256, 0, stream>>>(x, wb_enter, hbuf, hn2);
  gemm_bt<0><<<dim3(22, 64), 256, 0, stream>>>(hn2, wqkvT, 8192, 2816, 1024, qbuf, nullptr,
                                               nullptr, kvp, Q_LD);
  flash_attn<<<dim3(32, 8, 4), 256, 0, stream>>>(qbuf, kvp, attno);
  gemm_bt<1><<<dim3(4, 64), 256, 0, stream>>>(attno, woutT, 8192, 512, 4096, h2, nullptr, hbuf,
                                              nullptr, 512);
  gemm_bt<2><<<dim3(4, 64), 256, 0, stream>>>(h2, wfinT, 8192, 512, 512, nullptr, out, nullptr,
                                              nullptr, 512);
}

// Round 9
// 902.273 us; speedup vs baseline: 1.1464x; 1.1464x over previous
//
#include <hip/hip_runtime.h>

// GATrNet forward, MI355X/gfx950.
// Precision: q exact via f16 hi/lo split (hn hi/lo planes -> K=1024 qkv GEMM,
// q stored hi+lo); k stored f16-rounded (validated r8: absmax 4.1e4 < 6.26e4).
// Flash r9 = r6's proven structure (plain __syncthreads, single linear staging
// burst per tile) + r8's 48KB image (no k_lo) + r7's even vp swizzle and
// 8B V-stores. r8's raw-s_barrier pipeline and r7's flag-gating are reverted
// (both measured regressions: barrier convoys at 8 waves/CU cost more than
// the staged-drain they hide).

typedef unsigned short u16;
typedef unsigned int u32;
typedef __attribute__((ext_vector_type(4))) float f32x4;
typedef __attribute__((ext_vector_type(8))) _Float16 half8;

__device__ inline u16 f2h(float f) {
  _Float16 h = (_Float16)f;
  return __builtin_bit_cast(u16, h);
}
__device__ inline float h2f(u16 u) { return (float)__builtin_bit_cast(_Float16, u); }

// async global->LDS, 16B per lane. LDS dest = wave-uniform base + lane*16.
__device__ inline void async_cp16(const void* g, void* l) {
  __builtin_amdgcn_global_load_lds((const __attribute__((address_space(1))) u32*)g,
                                   (__attribute__((address_space(3))) u32*)l, 16, 0, 0);
}

__device__ inline f32x4 mfma16(half8 a, half8 b, f32x4 c) {
  return __builtin_amdgcn_mfma_f32_16x16x32_f16(a, b, c, 0, 0, 0);
}

// DPP row_ror move within 16-lane rows (reduction domain = lane&15).
template <int CTRL>
__device__ inline float dpp_mv(float v) {
  int i = __builtin_bit_cast(int, v);
  return __builtin_bit_cast(float, __builtin_amdgcn_update_dpp(i, i, CTRL, 0xf, 0xf, false));
}

// INNER_COORDS {0,2,3,4,8,9,10,14} packed 4b each
#define IC_PACK 0xEA984320u

// q buffer row: [q_hi 0,2048) [q_lo 2048,4096)
#define Q_LD 4096
// packed KV block per (b,tile): u16 offsets, stride 24576 (48KB)
//   kp [0,8192):     key*256 + (((d>>3)^(key&7))<<3) + (d&7)
//   vp [8192,24576): vd*32 + (((key>>3)^((vd>>1)&3))<<3) + (key&7)
#define KV_STRIDE 24576

// ---------------- weight prep ----------------
__global__ void build_wb_enter(const float* __restrict__ we, const float* __restrict__ blade,
                               float* __restrict__ out) {
  int idx = blockIdx.x * 256 + threadIdx.x;
  if (idx >= 32 * 48 * 16) return;
  int j = idx / 768;
  int rem = idx - j * 768;
  int ix = rem >> 4, y = rem & 15;
  int i = ix >> 4, x = ix & 15;
  float acc = 0.f;
#pragma unroll
  for (int bb = 0; bb < 9; ++bb) acc += we[j * 27 + i * 9 + bb] * blade[bb * 256 + x * 16 + y];
  out[idx] = acc;
}

// WqkvT[n][k] f16, K=1024 (k>=512 duplicates k-512 so GEMM computes (hi+lo)*w).
__global__ void build_wqkvT(const float* __restrict__ wq, const float* __restrict__ wk,
                            const float* __restrict__ wv, const float* __restrict__ blade,
                            u16* __restrict__ out) {
  int idx = blockIdx.x * 256 + threadIdx.x;
  if (idx >= 2816 * 1024) return;
  int k = idx & 1023, n = idx >> 10;
  int kk = k & 511;
  int i = kk >> 4, x = kk & 15;
  const float* w;
  int y;
  float scale = 1.0f;
  if (n < 2048) {
    int j = n >> 3;
    y = (IC_PACK >> ((n & 7) * 4)) & 15;
    w = wq + j * 288 + i * 9;
    scale = 0.09016844005556021f;  // (1/16)*log2(e)
  } else if (n < 2304) {
    int m = n - 2048;
    int j = m >> 3;
    y = (IC_PACK >> ((m & 7) * 4)) & 15;
    w = wk + j * 288 + i * 9;
  } else {
    int m = n - 2304;
    int j = m >> 4;
    y = m & 15;
    w = wv + j * 288 + i * 9;
  }
  float acc = 0.f;
#pragma unroll
  for (int bb = 0; bb < 9; ++bb) acc += w[bb] * blade[bb * 256 + x * 16 + y];
  out[idx] = f2h(acc * scale);
}

// WoutT[n][k] f16: n=(j,y)<512, k=(c,x)<4096
__global__ void build_woutT(const float* __restrict__ wo, const float* __restrict__ blade,
                            u16* __restrict__ out) {
  int idx = blockIdx.x * 256 + threadIdx.x;
  if (idx >= 512 * 4096) return;
  int k = idx & 4095, n = idx >> 12;
  int j = n >> 4, y = n & 15;
  int c = k >> 4, x = k & 15;
  float acc = 0.f;
#pragma unroll
  for (int bb = 0; bb < 9; ++bb) acc += wo[j * 2304 + c * 9 + bb] * blade[bb * 256 + x * 16 + y];
  out[idx] = f2h(acc);
}

// WfinalT[n][k] f16: n=(j,y)<512, k=(i,x)<512
__global__ void build_wfinalT(const float* __restrict__ wf, const float* __restrict__ blade,
                              u16* __restrict__ out) {
  int idx = blockIdx.x * 256 + threadIdx.x;
  if (idx >= 512 * 512) return;
  int k = idx & 511, n = idx >> 9;
  int j = n >> 4, y = n & 15;
  int i = k >> 4, x = k & 15;
  float acc = 0.f;
#pragma unroll
  for (int bb = 0; bb < 9; ++bb) acc += wf[j * 288 + i * 9 + bb] * blade[bb * 256 + x * 16 + y];
  out[idx] = f2h(acc);
}

// ---------------- enter projection + equi_norm ----------------
__global__ __launch_bounds__(256) void enter_norm(const float* __restrict__ x,
                                                  const float* __restrict__ wb,
                                                  float* __restrict__ h, u16* __restrict__ hn) {
  const int tid = threadIdx.x;
  const int tl = tid >> 5, j = tid & 31;
  const int token = blockIdx.x * 8 + tl;
  const float* xp = x + (size_t)token * 48;
  float xv[48];
#pragma unroll
  for (int q = 0; q < 12; ++q) {
    float4 t = ((const float4*)xp)[q];
    xv[q * 4 + 0] = t.x;
    xv[q * 4 + 1] = t.y;
    xv[q * 4 + 2] = t.z;
    xv[q * 4 + 3] = t.w;
  }
  float acc[16] = {};
  const float* wp = wb + j * 768;
#pragma unroll
  for (int t = 0; t < 48; ++t) {
    const float xs = xv[t];
    const float4* w4 = (const float4*)(wp + t * 16);
#pragma unroll
    for (int u = 0; u < 4; ++u) {
      float4 wv = w4[u];
      acc[u * 4 + 0] += xs * wv.x;
      acc[u * 4 + 1] += xs * wv.y;
      acc[u * 4 + 2] += xs * wv.z;
      acc[u * 4 + 3] += xs * wv.w;
    }
  }
  float ip = acc[0] * acc[0] + acc[2] * acc[2] + acc[3] * acc[3] + acc[4] * acc[4] +
             acc[8] * acc[8] + acc[9] * acc[9] + acc[10] * acc[10] + acc[14] * acc[14];
#pragma unroll
  for (int d = 1; d < 32; d <<= 1) ip += __shfl_xor(ip, d, 64);
  const float r = 1.0f / sqrtf(ip * (1.0f / 32.0f));
  float* hp = h + (size_t)token * 512 + j * 16;
#pragma unroll
  for (int u = 0; u < 4; ++u)
    ((float4*)hp)[u] = make_float4(acc[u * 4 + 0], acc[u * 4 + 1], acc[u * 4 + 2], acc[u * 4 + 3]);
  u16 hb[16], lb[16];
#pragma unroll
  for (int y = 0; y < 16; ++y) {
    float sv = acc[y] * r;
    u16 hv = f2h(sv);
    hb[y] = hv;
    lb[y] = f2h(sv - h2f(hv));
  }
  u16* hq = hn + (size_t)token * 1024 + j * 16;
  ((uint4*)hq)[0] = *(const uint4*)&hb[0];
  ((uint4*)hq)[1] = *(const uint4*)&hb[8];
  u16* lq = hq + 512;
  ((uint4*)lq)[0] = *(const uint4*)&lb[0];
  ((uint4*)lq)[1] = *(const uint4*)&lb[8];
}

// ---------------- 128x128 f16 MFMA GEMM, B transposed [N][K] ----------------
// MODE 0: qkv -> q hi/lo rows of Co (ldc=4096); k (f16) + v into packed kvp
//         blocks (48KB LDS-image layout, swizzle baked in; V 8B-vectorized)
// MODE 1: outp -> Co f16 = (acc + res)/256
// MODE 2: final-> Cf fp32 = acc*256
template <int MODE>
__global__ __launch_bounds__(256) void gemm_bt(const u16* __restrict__ A,
                                               const u16* __restrict__ BT, int M, int N, int K,
                                               u16* __restrict__ Co, float* __restrict__ Cf,
                                               const float* __restrict__ res,
                                               u16* __restrict__ kvp, int ldc) {
  __shared__ u16 ltA[4096];  // [128][32], chunk-swizzled
  __shared__ u16 ltB[4096];
  const int tid = threadIdx.x;
  const int lane = tid & 63;
  const int wid = tid >> 6;
  const int quad = lane >> 4, colc = lane & 15;
  const int m0 = blockIdx.y * 128, n0 = blockIdx.x * 128;
  const int wrow = (wid >> 1) * 64, wcol = (wid & 1) * 64;
  f32x4 acc[4][4] = {};
  const int r0 = tid >> 2;
  const int swk = (((tid & 3) ^ ((tid >> 2) & 3)) << 3);
  const u16* Ab = A + (size_t)(m0 + r0) * K + swk;
  const u16* Ab2 = Ab + (size_t)64 * K;
  const u16* Bb = BT + (size_t)(n0 + r0) * K + swk;
  const u16* Bb2 = Bb + (size_t)64 * K;
  const int swr = ((colc & 3) << 3);
  for (int k0 = 0; k0 < K; k0 += 32) {
    __syncthreads();
    async_cp16(Ab + k0, &ltA[tid * 8]);
    async_cp16(Ab2 + k0, &ltA[2048 + tid * 8]);
    async_cp16(Bb + k0, &ltB[tid * 8]);
    async_cp16(Bb2 + k0, &ltB[2048 + tid * 8]);
    __syncthreads();
    half8 af[4], bfr[4];
#pragma unroll
    for (int i2 = 0; i2 < 4; ++i2)
      af[i2] = *(const half8*)&ltA[(wrow + i2 * 16 + colc) * 32 + ((quad << 3) ^ swr)];
#pragma unroll
    for (int j2 = 0; j2 < 4; ++j2)
      bfr[j2] = *(const half8*)&ltB[(wcol + j2 * 16 + colc) * 32 + ((quad << 3) ^ swr)];
#pragma unroll
    for (int i2 = 0; i2 < 4; ++i2)
#pragma unroll
      for (int j2 = 0; j2 < 4; ++j2) acc[i2][j2] = mfma16(af[i2], bfr[j2], acc[i2][j2]);
  }
#pragma unroll
  for (int i2 = 0; i2 < 4; ++i2) {
#pragma unroll
    for (int j2 = 0; j2 < 4; ++j2) {
      const int mb = m0 + wrow + i2 * 16 + quad * 4;
      const int n = n0 + wcol + j2 * 16 + colc;
      if constexpr (MODE == 0) {
        if (n < 2048) {
#pragma unroll
          for (int rg = 0; rg < 4; ++rg) {
            const int m = mb + rg;
            float v = acc[i2][j2][rg];
            u16 hv = f2h(v);
            Co[(size_t)m * ldc + n] = hv;
            Co[(size_t)m * ldc + 2048 + n] = f2h(v - h2f(hv));
          }
        } else if (n < 2304) {
          const int d = n - 2048;
#pragma unroll
          for (int rg = 0; rg < 4; ++rg) {
            const int m = mb + rg;
            int bb2 = m >> 11, s = m & 2047, t = s >> 5, key = s & 31;
            size_t blk = (size_t)(bb2 * 64 + t) * KV_STRIDE;
            int off2 = key * 256 + ((((d >> 3) ^ (key & 7)) << 3)) + (d & 7);
            kvp[blk + off2] = f2h(acc[i2][j2][rg]);
          }
        } else {
          const int vd = n - 2304;
          int bb2 = mb >> 11, s0 = mb & 2047, t = s0 >> 5, key0 = s0 & 31;
          size_t blk = (size_t)(bb2 * 64 + t) * KV_STRIDE;
          u16 tmp[4];
#pragma unroll
          for (int rg = 0; rg < 4; ++rg) tmp[rg] = f2h(acc[i2][j2][rg]);
          size_t idx =
              blk + 8192 + vd * 32 + ((((key0 >> 3) ^ ((vd >> 1) & 3)) << 3)) + (key0 & 7);
          *(uint2*)&kvp[idx] = *(const uint2*)tmp;
        }
      } else {
#pragma unroll
        for (int rg = 0; rg < 4; ++rg) {
          const int m = mb + rg;
          float v = acc[i2][j2][rg];
          if constexpr (MODE == 1) {
            v += res[(size_t)m * ldc + n];
            Co[(size_t)m * ldc + n] = f2h(v * (1.0f / 256.0f));
          } else {
            Cf[(size_t)m * ldc + n] = v * 256.0f;
          }
        }
      }
    }
  }
}

// ---------------- flash attention ----------------
// grid (qblock=32, head=8, batch=4), 256 thr. Per tile (r6 structure):
//   B0 (__syncthreads: prev PV reads done) -> single linear 48KB stage burst
//   B1 (__syncthreads: drained)            -> S (32 MFMA) + softmax + pbuf
//   B2 (__syncthreads: pbuf published)     -> PV (rescale + 32 MFMA)
// Zero global loads in the loop; all operands from the staged LDS image.
__global__ __launch_bounds__(256, 2) void flash_attn(const u16* __restrict__ qbuf,
                                                     const u16* __restrict__ kvp,
                                                     u16* __restrict__ out) {
  __shared__ u16 lds[27392];
  u16* kp = lds;                            // [32 keys][256 d] swizzled, 16KB
  u16* vp = lds + 8192;                     // [512 vd][32 keys] swizzled, 32KB
  u16* pbuf = lds + 24576;                  // [64 qrow][40]
  float* alpha_s = (float*)(lds + 27136);   // 64 floats
  float* l_s = (float*)(lds + 27264);       // 64 floats
  const int tid = threadIdx.x, lane = tid & 63, wid = tid >> 6;
  const int quad = lane >> 4, colc = lane & 15;
  const int b = blockIdx.z, h = blockIdx.y, qb = blockIdx.x;
  half8 qh[8], ql[8];
  {
    const u16* qr = qbuf + (size_t)(b * 2048 + qb * 64 + wid * 16 + colc) * Q_LD + h * 8;
#pragma unroll
    for (int kb = 0; kb < 8; ++kb) {
      qh[kb] = *(const half8*)(qr + (kb * 4 + quad) * 64);
      ql[kb] = *(const half8*)(qr + 2048 + (kb * 4 + quad) * 64);
    }
  }
  f32x4 oacc[4][8] = {};
  float mrun[4], lrun[4];
#pragma unroll
  for (int rg = 0; rg < 4; ++rg) {
    mrun[rg] = -1e30f;
    lrun[rg] = 0.f;
  }
  const u16* kvb = kvp + (size_t)b * 64 * KV_STRIDE;
  const int x0 = colc & 7;
  for (int it = 0; it < 64; ++it) {
    __syncthreads();  // B0: prev tile's PV reads (vp/pbuf/alpha) complete
    {
      const u16* src = kvb + (size_t)it * KV_STRIDE;
#pragma unroll
      for (int c = 0; c < 12; ++c) {
        int e = c * 256 + tid;
        async_cp16(src + e * 8, &lds[e * 8]);
      }
    }
    __syncthreads();  // B1: stage drained
    // S [16q x 32k]: (qhi+qlo)*khi, 4 accumulation chains
    f32x4 s0a = {}, s0b = {}, s1a = {}, s1b = {};
#pragma unroll
    for (int kb = 0; kb < 8; ++kb) {
      const int sw = (((kb * 4 + quad) ^ x0) << 3);
      half8 khi0 = *(const half8*)&kp[colc * 256 + sw];
      half8 khi1 = *(const half8*)&kp[(16 + colc) * 256 + sw];
      s0a = mfma16(qh[kb], khi0, s0a);
      s0b = mfma16(ql[kb], khi0, s0b);
      s1a = mfma16(qh[kb], khi1, s1a);
      s1b = mfma16(ql[kb], khi1, s1b);
    }
    f32x4 sfr[2];
    sfr[0] = s0a + s0b;
    sfr[1] = s1a + s1b;
    // online softmax (exp2 domain), DPP row_ror butterflies over colc
    float mx[4];
#pragma unroll
    for (int rg = 0; rg < 4; ++rg) mx[rg] = fmaxf(sfr[0][rg], sfr[1][rg]);
#pragma unroll
    for (int rg = 0; rg < 4; ++rg) mx[rg] = fmaxf(mx[rg], dpp_mv<0x121>(mx[rg]));
#pragma unroll
    for (int rg = 0; rg < 4; ++rg) mx[rg] = fmaxf(mx[rg], dpp_mv<0x122>(mx[rg]));
#pragma unroll
    for (int rg = 0; rg < 4; ++rg) mx[rg] = fmaxf(mx[rg], dpp_mv<0x124>(mx[rg]));
#pragma unroll
    for (int rg = 0; rg < 4; ++rg) mx[rg] = fmaxf(mx[rg], dpp_mv<0x128>(mx[rg]));
    float al[4], pv0[4], pv1[4], rs[4];
#pragma unroll
    for (int rg = 0; rg < 4; ++rg) {
      float mn = fmaxf(mrun[rg], mx[rg]);
      al[rg] = exp2f(mrun[rg] - mn);
      mrun[rg] = mn;
      pv0[rg] = exp2f(sfr[0][rg] - mn);
      pv1[rg] = exp2f(sfr[1][rg] - mn);
      rs[rg] = pv0[rg] + pv1[rg];
    }
#pragma unroll
    for (int rg = 0; rg < 4; ++rg) rs[rg] += dpp_mv<0x121>(rs[rg]);
#pragma unroll
    for (int rg = 0; rg < 4; ++rg) rs[rg] += dpp_mv<0x122>(rs[rg]);
#pragma unroll
    for (int rg = 0; rg < 4; ++rg) rs[rg] += dpp_mv<0x124>(rs[rg]);
#pragma unroll
    for (int rg = 0; rg < 4; ++rg) rs[rg] += dpp_mv<0x128>(rs[rg]);
    const int prow = wid * 16 + quad * 4;
#pragma unroll
    for (int rg = 0; rg < 4; ++rg) {
      lrun[rg] = lrun[rg] * al[rg] + rs[rg];
      pbuf[(prow + rg) * 40 + colc] = f2h(pv0[rg]);
      pbuf[(prow + rg) * 40 + 16 + colc] = f2h(pv1[rg]);
    }
    if (colc == 0) {
#pragma unroll
      for (int rg = 0; rg < 4; ++rg) alpha_s[prow + rg] = al[rg];
    }
    __syncthreads();  // B2: pbuf/alpha published
    // PV: this wave's 128 v-dims, all 64 q-rows
    half8 vf[8];
#pragma unroll
    for (int vb = 0; vb < 8; ++vb) {
      const int vd = wid * 128 + vb * 16 + colc;
      vf[vb] = *(const half8*)&vp[vd * 32 + ((quad ^ ((vd >> 1) & 3)) << 3)];
    }
    half8 pf[4];
#pragma unroll
    for (int pa = 0; pa < 4; ++pa) pf[pa] = *(const half8*)&pbuf[(pa * 16 + colc) * 40 + quad * 8];
    float av[4][4];
#pragma unroll
    for (int pa = 0; pa < 4; ++pa)
#pragma unroll
      for (int rg = 0; rg < 4; ++rg) av[pa][rg] = alpha_s[pa * 16 + quad * 4 + rg];
#pragma unroll
    for (int pa = 0; pa < 4; ++pa)
#pragma unroll
      for (int vb = 0; vb < 8; ++vb)
#pragma unroll
        for (int rg = 0; rg < 4; ++rg) oacc[pa][vb][rg] *= av[pa][rg];
#pragma unroll
    for (int vb = 0; vb < 8; ++vb)
#pragma unroll
      for (int pa = 0; pa < 4; ++pa) oacc[pa][vb] = mfma16(pf[pa], vf[vb], oacc[pa][vb]);
  }
  {
    const int prow = wid * 16 + quad * 4;
    if (colc == 0) {
#pragma unroll
      for (int rg = 0; rg < 4; ++rg) l_s[prow + rg] = lrun[rg];
    }
  }
  __syncthreads();
  u16* ob = out + ((size_t)b * 2048 + qb * 64) * 4096 + h * 512 + wid * 128;
#pragma unroll
  for (int pa = 0; pa < 4; ++pa) {
    float li[4];
#pragma unroll
    for (int rg = 0; rg < 4; ++rg) li[rg] = 1.0f / l_s[pa * 16 + quad * 4 + rg];
#pragma unroll
    for (int vb = 0; vb < 8; ++vb)
#pragma unroll
      for (int rg = 0; rg < 4; ++rg)
        ob[(size_t)(pa * 16 + quad * 4 + rg) * 4096 + vb * 16 + colc] =
            f2h(oacc[pa][vb][rg] * li[rg]);
  }
}

// ---------------- launcher ----------------
extern "C" void kernel_launch(void* const* d_in, const int* in_sizes, int n_in, void* d_out,
                              int out_size, void* d_ws, size_t ws_size, hipStream_t stream) {
  const float* x = (const float*)d_in[0];
  const float* blade = (const float*)d_in[1];
  const float* w_enter = (const float*)d_in[2];
  const float* w_q = (const float*)d_in[3];
  const float* w_k = (const float*)d_in[4];
  const float* w_v = (const float*)d_in[5];
  const float* w_out = (const float*)d_in[6];
  const float* w_final = (const float*)d_in[7];
  float* out = (float*)d_out;

  char* ws = (char*)d_ws;
  size_t off = 0;
  auto alloc = [&](size_t bytes) {
    void* p = ws + off;
    off = (off + bytes + 255) & ~(size_t)255;
    return p;
  };
  float* wb_enter = (float*)alloc((size_t)32 * 48 * 16 * 4);
  u16* wqkvT = (u16*)alloc((size_t)2816 * 1024 * 2);
  u16* woutT = (u16*)alloc((size_t)512 * 4096 * 2);
  u16* wfinT = (u16*)alloc((size_t)512 * 512 * 2);
  float* hbuf = (float*)alloc((size_t)8192 * 512 * 4);
  u16* hn2 = (u16*)alloc((size_t)8192 * 1024 * 2);
  u16* qbuf = (u16*)alloc((size_t)8192 * Q_LD * 2);
  u16* kvp = (u16*)alloc((size_t)4 * 64 * KV_STRIDE * 2);
  u16* attno = (u16*)alloc((size_t)8192 * 4096 * 2);
  u16* h2 = (u16*)alloc((size_t)8192 * 512 * 2);

  build_wb_enter<<<96, 256, 0, stream>>>(w_enter, blade, wb_enter);
  build_wqkvT<<<11264, 256, 0, stream>>>(w_q, w_k, w_v, blade, wqkvT);
  build_woutT<<<8192, 256, 0, stream>>>(w_out, blade, woutT);
  build_wfinalT<<<1024, 256, 0, stream>>>(w_final, blade, wfinT);
  enter_norm<<<1024, 256, 0, stream>>>(x, wb_enter, hbuf, hn2);
  gemm_bt<0><<<dim3(22, 64), 256, 0, stream>>>(hn2, wqkvT, 8192, 2816, 1024, qbuf, nullptr,
                                               nullptr, kvp, Q_LD);
  flash_attn<<<dim3(32, 8, 4), 256, 0, stream>>>(qbuf, kvp, attno);
  gemm_bt<1><<<dim3(4, 64), 256, 0, stream>>>(attno, woutT, 8192, 512, 4096, h2, nullptr, hbuf,
                                              nullptr, 512);
  gemm_bt<2><<<dim3(4, 64), 256, 0, stream>>>(h2, wfinT, 8192, 512, 512, nullptr, out, nullptr,
                                              nullptr, 512);
}